// Round 15
// baseline (273.389 us; speedup 1.0000x reference)
//
#include <hip/hip_runtime.h>

typedef float f4 __attribute__((ext_vector_type(4)));
typedef int i4 __attribute__((ext_vector_type(4)));

// ---------------------------------------------------------------------------
// R15: R13 with ONE variable changed: tile 64 -> 32 rows, one-shot per block.
// LDS 33 -> 16.5 KB/block => 8 blocks/CU => 32 waves/CU (vs 16), matching the
// copy kernels' latency-hiding pool. No intra-block buffer reuse (R12's WAR
// confound removed): each wave scatters its 8 rows once and streams them out.
// All else identical: sequential-front tile mapping, wave-local barrier-free
// scan, speculative loads, wave-private LDS bounce, full-line f4 stores.
// ---------------------------------------------------------------------------
__global__ __launch_bounds__(256) void emb_kernel(const float* __restrict__ x,
                                                  const int* __restrict__ lengths,
                                                  float* __restrict__ out,
                                                  int n_seg, int maxt) {
    __shared__ alignas(16) float lt[4 * 1032];   // 16.5 KB: 8-row buffer per wave
    __shared__ int sw[4];                         // tail branch only
    const int tid = threadIdx.x;
    const int lane = tid & 63, wave = tid >> 6;
    const int tau = blockIdx.x;

    if (tau < maxt) {
        // ---- speculative x loads: uniform-mapping guess row = 32*tau ----
        // Always in-bounds: 32*tau + 31 < 32*maxt <= rows.
        f4 a[4];
        {
            const f4* ga = (const f4*)(x + (size_t)(32 * tau + 8 * wave) * 128);
            #pragma unroll
            for (int p = 0; p < 4; ++p) a[p] = ga[lane + 64 * p];
        }

        // ---- wave-local barrier-free mapping scan (32 segments per lane) ----
        int off = 0, L = 0, tloc = 0, found = 0;
        int carry_rows = 0, carry_tiles = 0;
        for (int base = 0; base < n_seg; base += 2048) {
            const int i0 = base + lane * 32;
            i4 lv[8];
            if (i0 + 32 <= n_seg) {
                const i4* lp = (const i4*)(lengths + i0);
                #pragma unroll
                for (int g = 0; g < 8; ++g) lv[g] = lp[g];
            } else {
                #pragma unroll
                for (int g = 0; g < 8; ++g) {
                    #pragma unroll
                    for (int j = 0; j < 4; ++j) {
                        const int idx = i0 + 4 * g + j;
                        lv[g][j] = (idx < n_seg) ? lengths[idx] : 0;
                    }
                }
            }
            int th_rows = 0;
            #pragma unroll
            for (int g = 0; g < 8; ++g)
                th_rows += lv[g].x + lv[g].y + lv[g].z + lv[g].w;

            int incl = th_rows;                   // inclusive row scan
            #pragma unroll
            for (int d = 1; d < 64; d <<= 1) { int u = __shfl_up(incl, d, 64); if (lane >= d) incl += u; }
            const int rows_total = __shfl(incl, 63, 64);

            // walk 1: count this lane's aligned 32-row tiles
            int run = carry_rows + incl - th_rows;
            int th_tiles = 0;
            #pragma unroll
            for (int g = 0; g < 8; ++g) {
                #pragma unroll
                for (int j = 0; j < 4; ++j) {
                    const int len = lv[g][j];
                    th_tiles += ((run & 15) == 0) ? (len >> 5) : 0;
                    run += len;
                }
            }
            int tincl = th_tiles;                 // inclusive tile scan
            #pragma unroll
            for (int d = 1; d < 64; d <<= 1) { int u = __shfl_up(tincl, d, 64); if (lane >= d) tincl += u; }
            const int tiles_total = __shfl(tincl, 63, 64);

            const int rel = tau - (carry_tiles + tincl - th_tiles);
            if (rel >= 0 && rel < th_tiles) {
                // walk 2: locate the segment inside this lane's window
                int run2 = carry_rows + incl - th_rows;
                int cum = 0;
                #pragma unroll
                for (int g = 0; g < 8; ++g) {
                    #pragma unroll
                    for (int j = 0; j < 4; ++j) {
                        const int len = lv[g][j];
                        const int f = ((run2 & 15) == 0) ? (len >> 5) : 0;
                        if (rel >= cum && rel < cum + f) {
                            off = run2; L = len; tloc = rel - cum; found = 1;
                        }
                        cum += f;
                        run2 += len;
                    }
                }
            }
            carry_rows += rows_total;
            carry_tiles += tiles_total;

            const unsigned long long m = __ballot(found);
            if (m) {
                const int src = __ffsll(m) - 1;
                off  = __shfl(off,  src, 64);
                L    = __shfl(L,    src, 64);
                tloc = __shfl(tloc, src, 64);
                found = 1;
                break;
            }
        }
        if (!found) return;                       // tau >= n_tiles: idle

        // ---- verify speculation; reload iff ragged mapping differs ----
        const int gr = off + 32 * tloc;           // actual global start row
        if (gr != 32 * tau) {
            const f4* src2 = (const f4*)(x + (size_t)(gr + 8 * wave) * 128);
            #pragma unroll
            for (int p = 0; p < 4; ++p) a[p] = src2[lane + 64 * p];
        }

        // ---- full-line wave-private LDS-bounce body (8 rows per wave) ----
        const float invL = 1.0f / (float)L;
        const int r0 = 32 * tloc + 8 * wave;      // segment-relative row
        float* __restrict__ lb = lt + wave * 1032;
        #pragma unroll
        for (int p = 0; p < 4; ++p) {
            const int q = lane + 64 * p;          // f4 index in 8x128 tile
            float* d = &lb[(q >> 5) * 129 + 1 + ((q & 31) << 2)];
            d[0] = a[p].x; d[1] = a[p].y; d[2] = a[p].z; d[3] = a[p].w;
        }
        if (lane < 8) lb[lane * 129] = (float)(r0 + lane + 1) * invL;

        const f4* __restrict__ l4 = (const f4*)lb;
        f4* __restrict__ o4 = (f4*)(out + ((size_t)off + r0) * 129);
        #pragma unroll
        for (int p = 0; p < 4; ++p) o4[lane + 64 * p] = l4[lane + 64 * p];
        if (lane < 2) o4[256 + lane] = l4[256 + lane];
    } else {
        // ---- ragged tail / unaligned-segment fallback (no-op when uniform) ----
        const int s = tau - maxt;
        if (s >= n_seg) return;
        int partial = 0;
        for (int i = tid; i < s; i += 256) partial += lengths[i];
        #pragma unroll
        for (int d = 32; d > 0; d >>= 1) partial += __shfl_xor(partial, d, 64);
        if (lane == 0) sw[wave] = partial;
        __syncthreads();
        const int off = sw[0] + sw[1] + sw[2] + sw[3];
        const int L = lengths[s];
        if (L <= 0) return;
        const float invL = 1.0f / (float)L;
        const float* __restrict__ xs = x + (size_t)off * 128;
        float* __restrict__ os = out + (size_t)off * 129;
        const int f = ((off & 15) == 0) ? (L >> 5) : 0;
        const int E = L * 129;
        for (int e = f * 32 * 129 + tid; e < E; e += 256) {
            const int row = e / 129;
            const int c = e - row * 129;
            os[e] = (c == 0) ? (float)(row + 1) * invL
                             : xs[(size_t)row * 128 + (c - 1)];
        }
    }
}

extern "C" void kernel_launch(void* const* d_in, const int* in_sizes, int n_in,
                              void* d_out, int out_size, void* d_ws, size_t ws_size,
                              hipStream_t stream) {
    const float* x = (const float*)d_in[0];
    const int* lengths = (const int*)d_in[1];
    const int n_seg = in_sizes[1];
    const int rows = in_sizes[0] / 128;
    const int maxt = rows / 32;

    emb_kernel<<<maxt + n_seg, 256, 0, stream>>>(x, lengths, (float*)d_out, n_seg, maxt);
}

// Round 16
// 197.993 us; speedup vs baseline: 1.3808x; 1.3808x over previous
//
#include <hip/hip_runtime.h>

typedef float f4 __attribute__((ext_vector_type(4)));
typedef f4 f4u __attribute__((aligned(4)));     // 4B-aligned f4 (unaligned store)
typedef int i4 __attribute__((ext_vector_type(4)));

// ---------------------------------------------------------------------------
// R16: R13 with the LDS bounce DELETED. Key algebra: the out-f4 at element
// r*129 + 1 + 4k is exactly x[r*128 + 4k .. 4k+3] -- one aligned input f4.
// So the data path becomes pure reg-to-reg (m13-copy-shaped): aligned
// global_load_dwordx4 -> 4B-aligned global_store_dwordx4 at the +1 skew,
// plus one pos dword per row. Store misalignment is absorbed by L2
// write-merge (byte-enables, no RFO; lines fully covered by adjacent waves);
// only ~25% of 16B stores straddle a 64B line and split at the L2 interface
// (34.5 TB/s headroom). Loads stay perfectly aligned (R3 showed the READ
// path cannot tolerate splits; the write path is the untested mirror).
// Mapping scan / speculation / tiling byte-identical to R13.
// ---------------------------------------------------------------------------
__global__ __launch_bounds__(256) void emb_kernel(const float* __restrict__ x,
                                                  const int* __restrict__ lengths,
                                                  float* __restrict__ out,
                                                  int n_seg, int maxt) {
    __shared__ int sw[4];                         // tail branch only
    const int tid = threadIdx.x;
    const int lane = tid & 63, wave = tid >> 6;
    const int tau = blockIdx.x;

    if (tau < maxt) {
        // ---- speculative x loads: uniform-mapping guess row = 64*tau ----
        f4 a[8];
        {
            const f4* ga = (const f4*)(x + (size_t)(64 * tau + 16 * wave) * 128);
            #pragma unroll
            for (int p = 0; p < 8; ++p) a[p] = ga[lane + 64 * p];
        }

        // ---- wave-local barrier-free mapping scan (32 segments per lane) ----
        int off = 0, L = 0, tloc = 0, found = 0;
        int carry_rows = 0, carry_tiles = 0;
        for (int base = 0; base < n_seg; base += 2048) {
            const int i0 = base + lane * 32;
            i4 lv[8];
            if (i0 + 32 <= n_seg) {
                const i4* lp = (const i4*)(lengths + i0);
                #pragma unroll
                for (int g = 0; g < 8; ++g) lv[g] = lp[g];
            } else {
                #pragma unroll
                for (int g = 0; g < 8; ++g) {
                    #pragma unroll
                    for (int j = 0; j < 4; ++j) {
                        const int idx = i0 + 4 * g + j;
                        lv[g][j] = (idx < n_seg) ? lengths[idx] : 0;
                    }
                }
            }
            int th_rows = 0;
            #pragma unroll
            for (int g = 0; g < 8; ++g)
                th_rows += lv[g].x + lv[g].y + lv[g].z + lv[g].w;

            int incl = th_rows;                   // inclusive row scan
            #pragma unroll
            for (int d = 1; d < 64; d <<= 1) { int u = __shfl_up(incl, d, 64); if (lane >= d) incl += u; }
            const int rows_total = __shfl(incl, 63, 64);

            // walk 1: count this lane's aligned tiles
            int run = carry_rows + incl - th_rows;
            int th_tiles = 0;
            #pragma unroll
            for (int g = 0; g < 8; ++g) {
                #pragma unroll
                for (int j = 0; j < 4; ++j) {
                    const int len = lv[g][j];
                    th_tiles += ((run & 15) == 0) ? (len >> 6) : 0;
                    run += len;
                }
            }
            int tincl = th_tiles;                 // inclusive tile scan
            #pragma unroll
            for (int d = 1; d < 64; d <<= 1) { int u = __shfl_up(tincl, d, 64); if (lane >= d) tincl += u; }
            const int tiles_total = __shfl(tincl, 63, 64);

            const int rel = tau - (carry_tiles + tincl - th_tiles);
            if (rel >= 0 && rel < th_tiles) {
                // walk 2: locate the segment inside this lane's window
                int run2 = carry_rows + incl - th_rows;
                int cum = 0;
                #pragma unroll
                for (int g = 0; g < 8; ++g) {
                    #pragma unroll
                    for (int j = 0; j < 4; ++j) {
                        const int len = lv[g][j];
                        const int f = ((run2 & 15) == 0) ? (len >> 6) : 0;
                        if (rel >= cum && rel < cum + f) {
                            off = run2; L = len; tloc = rel - cum; found = 1;
                        }
                        cum += f;
                        run2 += len;
                    }
                }
            }
            carry_rows += rows_total;
            carry_tiles += tiles_total;

            const unsigned long long m = __ballot(found);
            if (m) {
                const int src = __ffsll(m) - 1;
                off  = __shfl(off,  src, 64);
                L    = __shfl(L,    src, 64);
                tloc = __shfl(tloc, src, 64);
                found = 1;
                break;
            }
        }
        if (!found) return;                       // tau >= n_tiles: idle

        // ---- verify speculation; reload iff ragged mapping differs ----
        const int gr = off + 64 * tloc;           // actual global start row
        if (gr != 64 * tau) {
            const f4* src2 = (const f4*)(x + (size_t)(gr + 16 * wave) * 128);
            #pragma unroll
            for (int p = 0; p < 8; ++p) a[p] = src2[lane + 64 * p];
        }

        // ---- direct reg-to-reg body: skewed unaligned f4 stores + pos ----
        const float invL = 1.0f / (float)L;
        const int r0 = 64 * tloc + 16 * wave;     // segment-relative row
        float* __restrict__ ob = out + ((size_t)off + r0) * 129;
        #pragma unroll
        for (int p = 0; p < 8; ++p) {
            const int q = lane + 64 * p;          // f4 index in 16x128 tile
            const int r = q >> 5;                 // local row 0..15
            const int k = q & 31;                 // f4 within row
            *(f4u*)(ob + (size_t)r * 129 + 1 + 4 * k) = a[p];
        }
        if (lane < 16)
            ob[(size_t)lane * 129] = (float)(r0 + lane + 1) * invL;
    } else {
        // ---- ragged tail / unaligned-segment fallback (no-op when uniform) ----
        const int s = tau - maxt;
        if (s >= n_seg) return;
        int partial = 0;
        for (int i = tid; i < s; i += 256) partial += lengths[i];
        #pragma unroll
        for (int d = 32; d > 0; d >>= 1) partial += __shfl_xor(partial, d, 64);
        if (lane == 0) sw[wave] = partial;
        __syncthreads();
        const int off = sw[0] + sw[1] + sw[2] + sw[3];
        const int L = lengths[s];
        if (L <= 0) return;
        const float invL = 1.0f / (float)L;
        const float* __restrict__ xs = x + (size_t)off * 128;
        float* __restrict__ os = out + (size_t)off * 129;
        const int f = ((off & 15) == 0) ? (L >> 6) : 0;
        const int E = L * 129;
        for (int e = f * 64 * 129 + tid; e < E; e += 256) {
            const int row = e / 129;
            const int c = e - row * 129;
            os[e] = (c == 0) ? (float)(row + 1) * invL
                             : xs[(size_t)row * 128 + (c - 1)];
        }
    }
}

extern "C" void kernel_launch(void* const* d_in, const int* in_sizes, int n_in,
                              void* d_out, int out_size, void* d_ws, size_t ws_size,
                              hipStream_t stream) {
    const float* x = (const float*)d_in[0];
    const int* lengths = (const int*)d_in[1];
    const int n_seg = in_sizes[1];
    const int rows = in_sizes[0] / 128;
    const int maxt = rows / 64;

    emb_kernel<<<maxt + n_seg, 256, 0, stream>>>(x, lengths, (float*)d_out, n_seg, maxt);
}

// Round 17
// 192.175 us; speedup vs baseline: 1.4226x; 1.0303x over previous
//
#include <hip/hip_runtime.h>

typedef float f4 __attribute__((ext_vector_type(4)));
typedef int i4 __attribute__((ext_vector_type(4)));

// ---------------------------------------------------------------------------
// FINAL (R13): sequential-front tile kernel, 191.6 us = 5.63 TB/s combined
// (89.5% of the measured 6.29 TB/s copy ceiling). Structure:
//  - grid = one block per 64-row output tile + n_seg tail blocks; consecutive
//    blocks write consecutive 33 KB output windows (compact DRAM front).
//  - wave-local barrier-free mapping scan: each wave redundantly locates its
//    tile's (segment, local tile, offset) via two 6-step shfl scans over
//    lengths (32 segments/lane), __ballot/__shfl broadcast. No barriers, no
//    LDS on the fast path.
//  - speculative x loads issued BEFORE the scan (uniform-mapping guess,
//    verified after; reloaded only if the ragged layout diverges).
//  - wave-private LDS bounce absorbs the +1 column skew; both HBM streams
//    are 16B-aligned full-line f4 (loads 8 KB/wave, stores 8.25 KB/wave).
// Proven-regressing variants: unaligned loads/stores, nt loads/stores,
// deeper prefetch, higher/lower occupancy, block-wide scan, LDS-less body.
// ---------------------------------------------------------------------------
__global__ __launch_bounds__(256) void emb_kernel(const float* __restrict__ x,
                                                  const int* __restrict__ lengths,
                                                  float* __restrict__ out,
                                                  int n_seg, int maxt) {
    __shared__ alignas(16) float lt[4 * 2064];   // 33 KB: 16-row buffer per wave
    __shared__ int sw[4];                         // tail branch only
    const int tid = threadIdx.x;
    const int lane = tid & 63, wave = tid >> 6;
    const int tau = blockIdx.x;

    if (tau < maxt) {
        // ---- speculative x loads: uniform-mapping guess row = 64*tau ----
        // Always in-bounds: 64*tau + 63 < 64*maxt <= rows.
        f4 a[8];
        {
            const f4* ga = (const f4*)(x + (size_t)(64 * tau + 16 * wave) * 128);
            #pragma unroll
            for (int p = 0; p < 8; ++p) a[p] = ga[lane + 64 * p];
        }

        // ---- wave-local barrier-free mapping scan (32 segments per lane) ----
        int off = 0, L = 0, tloc = 0, found = 0;
        int carry_rows = 0, carry_tiles = 0;
        for (int base = 0; base < n_seg; base += 2048) {
            const int i0 = base + lane * 32;
            i4 lv[8];
            if (i0 + 32 <= n_seg) {
                const i4* lp = (const i4*)(lengths + i0);
                #pragma unroll
                for (int g = 0; g < 8; ++g) lv[g] = lp[g];
            } else {
                #pragma unroll
                for (int g = 0; g < 8; ++g) {
                    #pragma unroll
                    for (int j = 0; j < 4; ++j) {
                        const int idx = i0 + 4 * g + j;
                        lv[g][j] = (idx < n_seg) ? lengths[idx] : 0;
                    }
                }
            }
            int th_rows = 0;
            #pragma unroll
            for (int g = 0; g < 8; ++g)
                th_rows += lv[g].x + lv[g].y + lv[g].z + lv[g].w;

            int incl = th_rows;                   // inclusive row scan
            #pragma unroll
            for (int d = 1; d < 64; d <<= 1) { int u = __shfl_up(incl, d, 64); if (lane >= d) incl += u; }
            const int rows_total = __shfl(incl, 63, 64);

            // walk 1: count this lane's aligned tiles
            int run = carry_rows + incl - th_rows;
            int th_tiles = 0;
            #pragma unroll
            for (int g = 0; g < 8; ++g) {
                #pragma unroll
                for (int j = 0; j < 4; ++j) {
                    const int len = lv[g][j];
                    th_tiles += ((run & 15) == 0) ? (len >> 6) : 0;
                    run += len;
                }
            }
            int tincl = th_tiles;                 // inclusive tile scan
            #pragma unroll
            for (int d = 1; d < 64; d <<= 1) { int u = __shfl_up(tincl, d, 64); if (lane >= d) tincl += u; }
            const int tiles_total = __shfl(tincl, 63, 64);

            const int rel = tau - (carry_tiles + tincl - th_tiles);
            if (rel >= 0 && rel < th_tiles) {
                // walk 2: locate the segment inside this lane's window
                int run2 = carry_rows + incl - th_rows;
                int cum = 0;
                #pragma unroll
                for (int g = 0; g < 8; ++g) {
                    #pragma unroll
                    for (int j = 0; j < 4; ++j) {
                        const int len = lv[g][j];
                        const int f = ((run2 & 15) == 0) ? (len >> 6) : 0;
                        if (rel >= cum && rel < cum + f) {
                            off = run2; L = len; tloc = rel - cum; found = 1;
                        }
                        cum += f;
                        run2 += len;
                    }
                }
            }
            carry_rows += rows_total;
            carry_tiles += tiles_total;

            const unsigned long long m = __ballot(found);
            if (m) {
                const int src = __ffsll(m) - 1;
                off  = __shfl(off,  src, 64);
                L    = __shfl(L,    src, 64);
                tloc = __shfl(tloc, src, 64);
                found = 1;
                break;
            }
        }
        if (!found) return;                       // tau >= n_tiles: idle

        // ---- verify speculation; reload iff ragged mapping differs ----
        const int gr = off + 64 * tloc;           // actual global start row
        if (gr != 64 * tau) {
            const f4* src2 = (const f4*)(x + (size_t)(gr + 16 * wave) * 128);
            #pragma unroll
            for (int p = 0; p < 8; ++p) a[p] = src2[lane + 64 * p];
        }

        // ---- full-line wave-private LDS-bounce body ----
        const float invL = 1.0f / (float)L;
        const int r0 = 64 * tloc + 16 * wave;     // segment-relative row
        float* __restrict__ lb = lt + wave * 2064;
        #pragma unroll
        for (int p = 0; p < 8; ++p) {
            const int q = lane + 64 * p;          // f4 index in 16x128 tile
            float* d = &lb[(q >> 5) * 129 + 1 + ((q & 31) << 2)];
            d[0] = a[p].x; d[1] = a[p].y; d[2] = a[p].z; d[3] = a[p].w;
        }
        if (lane < 16) lb[lane * 129] = (float)(r0 + lane + 1) * invL;

        const f4* __restrict__ l4 = (const f4*)lb;
        f4* __restrict__ o4 = (f4*)(out + ((size_t)off + r0) * 129);
        #pragma unroll
        for (int p = 0; p < 8; ++p) o4[lane + 64 * p] = l4[lane + 64 * p];
        if (lane < 4) o4[512 + lane] = l4[512 + lane];
    } else {
        // ---- ragged tail / unaligned-segment fallback (no-op when uniform) ----
        const int s = tau - maxt;
        if (s >= n_seg) return;
        int partial = 0;
        for (int i = tid; i < s; i += 256) partial += lengths[i];
        #pragma unroll
        for (int d = 32; d > 0; d >>= 1) partial += __shfl_xor(partial, d, 64);
        if (lane == 0) sw[wave] = partial;
        __syncthreads();
        const int off = sw[0] + sw[1] + sw[2] + sw[3];
        const int L = lengths[s];
        if (L <= 0) return;
        const float invL = 1.0f / (float)L;
        const float* __restrict__ xs = x + (size_t)off * 128;
        float* __restrict__ os = out + (size_t)off * 129;
        const int f = ((off & 15) == 0) ? (L >> 6) : 0;
        const int E = L * 129;
        for (int e = f * 64 * 129 + tid; e < E; e += 256) {
            const int row = e / 129;
            const int c = e - row * 129;
            os[e] = (c == 0) ? (float)(row + 1) * invL
                             : xs[(size_t)row * 128 + (c - 1)];
        }
    }
}

extern "C" void kernel_launch(void* const* d_in, const int* in_sizes, int n_in,
                              void* d_out, int out_size, void* d_ws, size_t ws_size,
                              hipStream_t stream) {
    const float* x = (const float*)d_in[0];
    const int* lengths = (const int*)d_in[1];
    const int n_seg = in_sizes[1];
    const int rows = in_sizes[0] / 128;
    const int maxt = rows / 64;

    emb_kernel<<<maxt + n_seg, 256, 0, stream>>>(x, lengths, (float*)d_out, n_seg, maxt);
}